// Round 25
// baseline (374.157 us; speedup 1.0000x reference)
//
#include <hip/hip_runtime.h>

// SPModel_6846177870356: y = x@W^T + all2all permute. M=28160, N=K=2048.
// Inputs FP32 (harness-upcast fp16), output FP32.
// Round 25 = R22's verified schedule at MULTI-BLOCK occupancy:
// BM=BN=128, 256 thr (4 waves 2x2, 64x64/wave), LDS 3x16KB=48KB -> 3
// blocks/CU (launch_bounds(256,3)); same row-pair 0-conflict layout, same
// stagger-2 triple-buffer, same one-counted-gate/tile ledger:
//   prologue: stage t0(4)+t1(4), VM(4)  [t0 certified, t1 flying]
//   p0: read A(t)+B(t,h0); stage A(t+2); BAR; LGKM0; 8 MFMA; BAR
//   p1: read B(t,h1);      stage B(t+2); VM(4) [drains t+1]; BAR; LGKM0;
//       8 MFMA; BAR; rotate
// m114: co-resident blocks overlap barrier/convoy stalls that 15 rounds of
// 1-blk scheduling could not remove. XCD swizzle, fused a2a f32 epilogue.

typedef _Float16 f16;
typedef _Float16 f16x2 __attribute__((ext_vector_type(2)));
typedef _Float16 f16x8 __attribute__((ext_vector_type(8)));
typedef float    f32x4 __attribute__((ext_vector_type(4)));

#define GPTR(p) ((const __attribute__((address_space(1))) void*)(p))
#define LPTR(p) ((__attribute__((address_space(3))) void*)(p))

constexpr int Mdim = 28160;   // 8*44*80
constexpr int Ndim = 2048;
constexpr int Kdim = 2048;
constexpr int BM = 128, BN = 128, BK = 32;
constexpr int NWG = (Mdim / BM) * (Ndim / BN);  // 220*16 = 3520 (%8==0)
constexpr int NT  = Kdim / BK;                  // 64
constexpr size_t XS_ELEMS = (size_t)Mdim * Kdim;
constexpr size_t WS_ELEMS = (size_t)Ndim * Kdim;
constexpr size_t WS_NEED  = (XS_ELEMS + WS_ELEMS) * sizeof(f16);

__device__ __forceinline__ f16x8 pack8(const f32x4& lo, const f32x4& hi) {
    f16x2 p0 = __builtin_bit_cast(f16x2, __builtin_amdgcn_cvt_pkrtz(lo[0], lo[1]));
    f16x2 p1 = __builtin_bit_cast(f16x2, __builtin_amdgcn_cvt_pkrtz(lo[2], lo[3]));
    f16x2 p2 = __builtin_bit_cast(f16x2, __builtin_amdgcn_cvt_pkrtz(hi[0], hi[1]));
    f16x2 p3 = __builtin_bit_cast(f16x2, __builtin_amdgcn_cvt_pkrtz(hi[2], hi[3]));
    return (f16x8){p0[0], p0[1], p1[0], p1[1], p2[0], p2[1], p3[0], p3[1]};
}

// plain linear f32 -> f16 convert (R11/R22-verified)
__global__ __launch_bounds__(256)
void convert_kernel(const float* __restrict__ src, f16* __restrict__ dst) {
    const size_t idx = ((size_t)blockIdx.x * 256 + threadIdx.x) * 8;
    f32x4 lo = *(const f32x4*)(src + idx);
    f32x4 hi = *(const f32x4*)(src + idx + 4);
    *(f16x8*)(dst + idx) = pack8(lo, hi);
}

// R11/R22-verified row-pair swizzled read: 0 bank conflicts on hardware.
__device__ __forceinline__ f16x8 lds_frag(const f16* base, int r, int kc) {
    const int line = r >> 1;
    const int b    = (((r & 1) << 6) + (kc << 1)) ^ ((line & 7) << 4);
    return *(const f16x8*)((const char*)base + line * 128 + b);
}

__global__ __launch_bounds__(256, 3)
void gemm_a2a_kernel(const f16* __restrict__ Xs, const f16* __restrict__ Ws,
                     float* __restrict__ out) {
    __shared__ f16 sA[3][BM * BK];   // 8 KiB each (row-pair swizzled image)
    __shared__ f16 sB[3][BN * BK];   // 8 KiB each  (total 48 KiB)

    const int tid  = threadIdx.x;
    const int lane = tid & 63;
    const int wid  = tid >> 6;
    const int wm   = wid >> 1;          // 0..1 -> 64 M-rows
    const int wn   = wid & 1;           // 0..1 -> 64 N-cols

    const int cpx  = NWG >> 3;                       // XCD-bijective swizzle
    const int tile = (blockIdx.x & 7) * cpx + (blockIdx.x >> 3);
    const int bn   = tile & 15;
    const int bm   = tile >> 4;
    const int row0 = bm * BM;
    const int col0 = bn * BN;

    const int lr = lane & 15;
    const int kq = (lane >> 4) * 8;     // k-offset within BK=32

    f32x4 acc[4][4] = {};

    // Staging: A tile = 128x32 f16 = 8KB = 2 chunks/thread; same for B.
    // dst = wave-uniform base + lane*16 (G21).
    const int betaA0 = tid * 16;
    const int betaA1 = 4096 + tid * 16;
    // Source offset for LDS byte beta (LINEAR globals, R11-verified mapping):
    auto srcoff = [&](int beta) {
        const int line = beta >> 7;
        const int u    = ((beta >> 4) & 7) ^ (line & 7);
        const int r    = 2 * line + (u >> 2);
        return (size_t)r * Kdim + (size_t)((u & 3) * 8);
    };
    const size_t sO0 = srcoff(betaA0), sO1 = srcoff(betaA1);
    const f16* Xb = Xs + (size_t)row0 * Kdim;
    const f16* Wb = Ws + (size_t)col0 * Kdim;

#define STAGE_A2(T, DA)                                                      \
    do {                                                                     \
        __builtin_amdgcn_global_load_lds(GPTR(Xb + sO0 + (T) * BK),          \
            LPTR((char*)(DA) + betaA0), 16, 0, 0);                           \
        __builtin_amdgcn_global_load_lds(GPTR(Xb + sO1 + (T) * BK),          \
            LPTR((char*)(DA) + betaA1), 16, 0, 0);                           \
    } while (0)
#define STAGE_B2(T, DB)                                                      \
    do {                                                                     \
        __builtin_amdgcn_global_load_lds(GPTR(Wb + sO0 + (T) * BK),          \
            LPTR((char*)(DB) + betaA0), 16, 0, 0);                           \
        __builtin_amdgcn_global_load_lds(GPTR(Wb + sO1 + (T) * BK),          \
            LPTR((char*)(DB) + betaA1), 16, 0, 0);                           \
    } while (0)

    f16x8 Af[4], Bf[2];
    auto readA = [&](const f16* base) {
#pragma unroll
        for (int f = 0; f < 4; ++f)
            Af[f] = lds_frag(base, wm * 64 + f * 16 + lr, kq);
    };
    auto readB = [&](const f16* base, int h) {
#pragma unroll
        for (int g = 0; g < 2; ++g)
            Bf[g] = lds_frag(base, wn * 64 + h * 32 + g * 16 + lr, kq);
    };

#define MFMA8(H)                                                            \
    do {                                                                    \
        __builtin_amdgcn_s_setprio(1);                                      \
        _Pragma("unroll")                                                   \
        for (int f = 0; f < 4; ++f)                                         \
            _Pragma("unroll")                                               \
            for (int g = 0; g < 2; ++g)                                     \
                acc[f][(H)*2 + g] =                                         \
                    __builtin_amdgcn_mfma_f32_16x16x32_f16(                 \
                        Af[f], Bf[g], acc[f][(H)*2 + g], 0, 0, 0);          \
        __builtin_amdgcn_s_setprio(0);                                      \
    } while (0)

#define VM(N)   asm volatile("s_waitcnt vmcnt(" #N ")" ::: "memory")
#define BAR()   __builtin_amdgcn_s_barrier()
#define LGKM0() do { asm volatile("s_waitcnt lgkmcnt(0)" ::: "memory");     \
                     __builtin_amdgcn_sched_barrier(0); } while (0)

    f16 *cA = sA[0], *nA = sA[1], *gA = sA[2];
    f16 *cB = sB[0], *nB = sB[1], *gB = sB[2];

    // Prologue: tile 0 -> buf0, tile 1 -> buf1 (8 loads); certify t0.
    STAGE_A2(0, cA); STAGE_B2(0, cB);
    STAGE_A2(1, nA); STAGE_B2(1, nB);
    VM(4); BAR();                       // t0 certified; t1's 4 in flight

    for (int t = 0; t < NT - 2; ++t) {
        // p0: n-half 0 — reads of tile t certified by previous tile's gate
        readA(cA); readB(cB, 0);
        STAGE_A2(t + 2, gA);            // 4 -> 6 outstanding
        BAR(); LGKM0();
        MFMA8(0);
        BAR();
        // p1: n-half 1 (A held in regs)
        readB(cB, 1);
        STAGE_B2(t + 2, gB);            // 6 -> 8
        VM(4); BAR(); LGKM0();          // drains tile t+1's 4 units (old)
        MFMA8(1);
        BAR();
        // rotate: cur <- next <- stage <- cur
        f16* tA = cA; cA = nA; nA = gA; gA = tA;
        f16* tB = cB; cB = nB; nB = gB; gB = tB;
    }
    // Peel t = NT-2: no staging; gate VM(0) certifies tile NT-1 (loads old).
    {
        readA(cA); readB(cB, 0);
        BAR(); LGKM0();
        MFMA8(0);
        BAR();
        readB(cB, 1);
        VM(0); BAR(); LGKM0();
        MFMA8(1);
        BAR();
        f16* tA = cA; cA = nA; nA = gA; gA = tA;
        f16* tB = cB; cB = nB; nB = gB; gB = tB;
    }
    // Peel t = NT-1: everything certified.
    {
        readA(cA); readB(cB, 0);
        BAR(); LGKM0();
        MFMA8(0);
        BAR();
        readB(cB, 1);
        LGKM0();
        MFMA8(1);
    }

    // Epilogue: C/D col=lane&15 (n), row=(lane>>4)*4+j (m); fused all2all:
    // out[(n>>8)*M*256 + m*256 + (n&255)], f32 stores.
    const int R0 = row0 + wm * 64;
    const int C0 = col0 + wn * 64;
#pragma unroll
    for (int mi = 0; mi < 4; ++mi)
#pragma unroll
        for (int ni = 0; ni < 4; ++ni) {
            const int n     = C0 + ni * 16 + lr;
            const int rbase = R0 + mi * 16 + (lane >> 4) * 4;
            const size_t obase = (size_t)(n >> 8) * ((size_t)Mdim * 256) + (n & 255);
#pragma unroll
            for (int j = 0; j < 4; ++j)
                out[obase + (size_t)(rbase + j) * 256] = acc[mi][ni][j];
        }
}

// ---- Fallback (R7-verified): direct-f32 reg-staged dbuf 128^2 kernel ----
constexpr int FBM = 128, FBK = 64;
constexpr int FNWG = (Mdim / FBM) * (Ndim / FBM);
__global__ __launch_bounds__(256)
void gemm_a2a_f32_kernel(const float* __restrict__ X, const float* __restrict__ W,
                         float* __restrict__ out) {
    __shared__ f16 sA[2][FBM * FBK];
    __shared__ f16 sB[2][FBM * FBK];
    const int tid  = threadIdx.x;
    const int lane = tid & 63;
    const int wid  = tid >> 6;
    const int wr   = wid >> 1;
    const int wc   = wid & 1;
    const int cpx  = FNWG >> 3;
    const int tile = (blockIdx.x & 7) * cpx + (blockIdx.x >> 3);
    const int bn   = tile & 15;
    const int bm   = tile >> 4;
    const int row0 = bm * FBM;
    const int col0 = bn * FBM;
    f32x4 acc[4][4] = {};
    f32x4 ra[8], rb[8];
    auto load_tile = [&](int t) {
#pragma unroll
        for (int i = 0; i < 4; ++i) {
            const int c8 = i * 256 + tid;
            const int r  = c8 >> 3;
            const int cc = (c8 & 7) * 8;
            const float* pa = X + (size_t)(row0 + r) * Kdim + t * FBK + cc;
            const float* pb = W + (size_t)(col0 + r) * Kdim + t * FBK + cc;
            ra[2*i] = *(const f32x4*)pa; ra[2*i+1] = *(const f32x4*)(pa + 4);
            rb[2*i] = *(const f32x4*)pb; rb[2*i+1] = *(const f32x4*)(pb + 4);
        }
    };
    int cur = 0;
    load_tile(0);
    for (int t = 0; t < Kdim / FBK; ++t) {
#pragma unroll
        for (int i = 0; i < 4; ++i) {
            const int c8 = i * 256 + tid;
            const int sb = (c8 * 16) ^ (((c8 >> 3) & 7) << 4);
            *(f16x8*)((char*)sA[cur] + sb) = pack8(ra[2*i], ra[2*i+1]);
            *(f16x8*)((char*)sB[cur] + sb) = pack8(rb[2*i], rb[2*i+1]);
        }
        if (t + 1 < Kdim / FBK) load_tile(t + 1);
        __syncthreads();
        const f16* Ab = sA[cur];
        const f16* Bb = sB[cur];
#pragma unroll
        for (int kk = 0; kk < FBK; kk += 32) {
            const int kc = kk + (lane >> 4) * 8;
            f16x8 af[4], bfr[4];
#pragma unroll
            for (int f = 0; f < 4; ++f) {
                const int rowA = wr * 64 + f * 16 + (lane & 15);
                af[f] = *(const f16x8*)((const char*)Ab + (((rowA * FBK + kc) * 2) ^ ((rowA & 7) << 4)));
                const int rowB = wc * 64 + f * 16 + (lane & 15);
                bfr[f] = *(const f16x8*)((const char*)Bb + (((rowB * FBK + kc) * 2) ^ ((rowB & 7) << 4)));
            }
#pragma unroll
            for (int mi = 0; mi < 4; ++mi)
#pragma unroll
                for (int ni = 0; ni < 4; ++ni)
                    acc[mi][ni] = __builtin_amdgcn_mfma_f32_16x16x32_f16(
                        af[mi], bfr[ni], acc[mi][ni], 0, 0, 0);
        }
        cur ^= 1;
    }
#pragma unroll
    for (int mi = 0; mi < 4; ++mi)
#pragma unroll
        for (int ni = 0; ni < 4; ++ni) {
            const int n     = col0 + wc * 64 + ni * 16 + (lane & 15);
            const int rbase = row0 + wr * 64 + mi * 16 + (lane >> 4) * 4;
            const size_t obase = (size_t)(n >> 8) * ((size_t)Mdim * 256) + (n & 255);
#pragma unroll
            for (int j = 0; j < 4; ++j)
                out[obase + (size_t)(rbase + j) * 256] = acc[mi][ni][j];
        }
}

extern "C" void kernel_launch(void* const* d_in, const int* in_sizes, int n_in,
                              void* d_out, int out_size, void* d_ws, size_t ws_size,
                              hipStream_t stream) {
    const float* X = (const float*)d_in[0];
    const float* W = (const float*)d_in[1];
    float* out     = (float*)d_out;
    if (ws_size >= WS_NEED) {
        f16* Xs = (f16*)d_ws;
        f16* Ws = Xs + XS_ELEMS;
        hipLaunchKernelGGL(convert_kernel, dim3((int)(XS_ELEMS / 8 / 256)), dim3(256),
                           0, stream, X, Xs);
        hipLaunchKernelGGL(convert_kernel, dim3((int)(WS_ELEMS / 8 / 256)), dim3(256),
                           0, stream, W, Ws);
        hipLaunchKernelGGL(gemm_a2a_kernel, dim3(NWG), dim3(256), 0, stream, Xs, Ws, out);
    } else {
        hipLaunchKernelGGL(gemm_a2a_f32_kernel, dim3(FNWG), dim3(256), 0, stream, X, W, out);
    }
}

// Round 26
// 333.140 us; speedup vs baseline: 1.1231x; 1.1231x over previous
//
#include <hip/hip_runtime.h>

// SPModel_6846177870356: y = x@W^T + all2all permute. M=28160, N=K=2048.
// Inputs FP32 (harness-upcast fp16), output FP32.
// FINAL (= R22/R24, measured best: GEMM 275us ~860 TF, total 333.5us,
// reproduced twice). Schedule: BK=32, triple-buffer, stagger-2, ONE vmcnt(4)
// gate per K-tile, reads pre-barrier, 2 barriers/phase, LGKM0+sched_barrier
// (rule #18), setprio (T5), R11 row-pair 0-conflict LDS layout (T2),
// XCD-bijective swizzle (T1), fused all2all f32 epilogue.
// A/B-refuted neighbors: 4-phase/3-gate (332), BN=128 (360), B-from-L2
// (519), batched-stage vmcnt(0) (385), 32x32x16 shape (302, bank conflicts),
// 3-blk/CU 128^2 (312). Residual ~60% MFMA idle = 2-phase stage+barrier
// overhead, structural to this family in plain HIP (m233).

typedef _Float16 f16;
typedef _Float16 f16x2 __attribute__((ext_vector_type(2)));
typedef _Float16 f16x8 __attribute__((ext_vector_type(8)));
typedef float    f32x4 __attribute__((ext_vector_type(4)));

#define GPTR(p) ((const __attribute__((address_space(1))) void*)(p))
#define LPTR(p) ((__attribute__((address_space(3))) void*)(p))

constexpr int Mdim = 28160;   // 8*44*80
constexpr int Ndim = 2048;
constexpr int Kdim = 2048;
constexpr int BM = 256, BN = 256, BK = 32;
constexpr int NWG = (Mdim / BM) * (Ndim / BN);  // 880 (%8==0)
constexpr int NT  = Kdim / BK;                  // 64
constexpr size_t XS_ELEMS = (size_t)Mdim * Kdim;
constexpr size_t WS_ELEMS = (size_t)Ndim * Kdim;
constexpr size_t WS_NEED  = (XS_ELEMS + WS_ELEMS) * sizeof(f16);

__device__ __forceinline__ f16x8 pack8(const f32x4& lo, const f32x4& hi) {
    f16x2 p0 = __builtin_bit_cast(f16x2, __builtin_amdgcn_cvt_pkrtz(lo[0], lo[1]));
    f16x2 p1 = __builtin_bit_cast(f16x2, __builtin_amdgcn_cvt_pkrtz(lo[2], lo[3]));
    f16x2 p2 = __builtin_bit_cast(f16x2, __builtin_amdgcn_cvt_pkrtz(hi[0], hi[1]));
    f16x2 p3 = __builtin_bit_cast(f16x2, __builtin_amdgcn_cvt_pkrtz(hi[2], hi[3]));
    return (f16x8){p0[0], p0[1], p1[0], p1[1], p2[0], p2[1], p3[0], p3[1]};
}

// plain linear f32 -> f16 convert (R11/R22-verified)
__global__ __launch_bounds__(256)
void convert_kernel(const float* __restrict__ src, f16* __restrict__ dst) {
    const size_t idx = ((size_t)blockIdx.x * 256 + threadIdx.x) * 8;
    f32x4 lo = *(const f32x4*)(src + idx);
    f32x4 hi = *(const f32x4*)(src + idx + 4);
    *(f16x8*)(dst + idx) = pack8(lo, hi);
}

// R11/R22-verified row-pair swizzled read: 0 bank conflicts on hardware.
__device__ __forceinline__ f16x8 lds_frag(const f16* base, int r, int kc) {
    const int line = r >> 1;
    const int b    = (((r & 1) << 6) + (kc << 1)) ^ ((line & 7) << 4);
    return *(const f16x8*)((const char*)base + line * 128 + b);
}

__global__ __launch_bounds__(512, 2)
void gemm_a2a_kernel(const f16* __restrict__ Xs, const f16* __restrict__ Ws,
                     float* __restrict__ out) {
    __shared__ f16 sA[3][BM * BK];   // 16 KiB each (row-pair swizzled image)
    __shared__ f16 sB[3][BN * BK];   // total 96 KiB

    const int tid  = threadIdx.x;
    const int lane = tid & 63;
    const int wid  = tid >> 6;
    const int wm   = wid >> 2;          // 0..1 -> 128 M-rows
    const int wn   = wid & 3;           // 0..3 -> 64 N-cols

    const int cpx  = NWG >> 3;                       // XCD-bijective swizzle
    const int tile = (blockIdx.x & 7) * cpx + (blockIdx.x >> 3);
    const int bn   = tile & 7;
    const int bm   = tile >> 3;
    const int row0 = bm * BM;
    const int col0 = bn * BN;

    const int lr = lane & 15;
    const int kq = (lane >> 4) * 8;     // k-offset within BK=32

    f32x4 acc[8][4] = {};

    // Units: A_u0 = tile rows {0-63}u{128-191}; A_u1 = +64; B_u0 = rows
    // 0-127; B_u1 = rows 128-255. dst = wave-uniform base + lane*16 (G21).
    const int betaA0 = (tid < 256) ? tid * 16 : 8192 + (tid - 256) * 16;
    const int betaA1 = betaA0 + 4096;
    const int betaB0 = tid * 16;
    const int betaB1 = 8192 + tid * 16;
    // Source offset for LDS byte beta (LINEAR globals, R11-verified mapping):
    auto srcoff = [&](int beta) {
        const int line = beta >> 7;
        const int u    = ((beta >> 4) & 7) ^ (line & 7);
        const int r    = 2 * line + (u >> 2);
        return (size_t)r * Kdim + (size_t)((u & 3) * 8);
    };
    const size_t sA0 = srcoff(betaA0), sA1 = srcoff(betaA1);
    const size_t sB0 = srcoff(betaB0), sB1 = srcoff(betaB1);
    const f16* Xb = Xs + (size_t)row0 * Kdim;
    const f16* Wb = Ws + (size_t)col0 * Kdim;

#define STAGE_A2(T, DA)                                                      \
    do {                                                                     \
        __builtin_amdgcn_global_load_lds(GPTR(Xb + sA0 + (T) * BK),          \
            LPTR((char*)(DA) + betaA0), 16, 0, 0);                           \
        __builtin_amdgcn_global_load_lds(GPTR(Xb + sA1 + (T) * BK),          \
            LPTR((char*)(DA) + betaA1), 16, 0, 0);                           \
    } while (0)
#define STAGE_B2(T, DB)                                                      \
    do {                                                                     \
        __builtin_amdgcn_global_load_lds(GPTR(Wb + sB0 + (T) * BK),          \
            LPTR((char*)(DB) + betaB0), 16, 0, 0);                           \
        __builtin_amdgcn_global_load_lds(GPTR(Wb + sB1 + (T) * BK),          \
            LPTR((char*)(DB) + betaB1), 16, 0, 0);                           \
    } while (0)

    f16x8 Af[4], Bf[4];
    auto readA = [&](const f16* base, int qm) {
#pragma unroll
        for (int f = 0; f < 4; ++f)
            Af[f] = lds_frag(base, wm * 128 + qm * 64 + f * 16 + lr, kq);
    };
    auto readB = [&](const f16* base) {
#pragma unroll
        for (int g = 0; g < 4; ++g)
            Bf[g] = lds_frag(base, wn * 64 + g * 16 + lr, kq);
    };

#define MFMA16(QM)                                                          \
    do {                                                                    \
        __builtin_amdgcn_s_setprio(1);                                      \
        _Pragma("unroll")                                                   \
        for (int f = 0; f < 4; ++f)                                         \
            _Pragma("unroll")                                               \
            for (int g = 0; g < 4; ++g)                                     \
                acc[(QM)*4 + f][g] =                                        \
                    __builtin_amdgcn_mfma_f32_16x16x32_f16(                 \
                        Af[f], Bf[g], acc[(QM)*4 + f][g], 0, 0, 0);         \
        __builtin_amdgcn_s_setprio(0);                                      \
    } while (0)

#define VM(N)   asm volatile("s_waitcnt vmcnt(" #N ")" ::: "memory")
#define BAR()   __builtin_amdgcn_s_barrier()
#define LGKM0() do { asm volatile("s_waitcnt lgkmcnt(0)" ::: "memory");     \
                     __builtin_amdgcn_sched_barrier(0); } while (0)

    f16 *cA = sA[0], *nA = sA[1], *gA = sA[2];
    f16 *cB = sB[0], *nB = sB[1], *gB = sB[2];

    // Prologue: stage tile 0 -> buf0, tile 1 -> buf1 (8 loads); certify t0.
    STAGE_A2(0, cA); STAGE_B2(0, cB);
    STAGE_A2(1, nA); STAGE_B2(1, nB);
    VM(4); BAR();                       // t0 certified; t1's 4 in flight

    for (int t = 0; t < NT - 2; ++t) {
        // p0: qm=0 — reads of tile t certified by previous tile's gate
        readA(cA, 0); readB(cB);
        STAGE_A2(t + 2, gA);
        BAR(); LGKM0();
        MFMA16(0);
        BAR();
        // p1: qm=1 (B held in regs)
        readA(cA, 1);
        STAGE_B2(t + 2, gB);
        VM(4); BAR(); LGKM0();          // drains tile t+1's 4 units (old)
        MFMA16(1);
        BAR();
        // rotate: cur <- next <- stage <- cur
        f16* tA = cA; cA = nA; nA = gA; gA = tA;
        f16* tB = cB; cB = nB; nB = gB; gB = tB;
    }
    // Peel t = NT-2: no staging; gate VM(0) certifies tile NT-1 (loads old).
    {
        readA(cA, 0); readB(cB);
        BAR(); LGKM0();
        MFMA16(0);
        BAR();
        readA(cA, 1);
        VM(0); BAR(); LGKM0();
        MFMA16(1);
        BAR();
        f16* tA = cA; cA = nA; nA = gA; gA = tA;
        f16* tB = cB; cB = nB; nB = gB; gB = tB;
    }
    // Peel t = NT-1: everything certified.
    {
        readA(cA, 0); readB(cB);
        BAR(); LGKM0();
        MFMA16(0);
        BAR();
        readA(cA, 1);
        LGKM0();
        MFMA16(1);
    }

    // Epilogue: C/D col=lane&15 (n), row=(lane>>4)*4+j (m); fused all2all:
    // out[(n>>8)*M*256 + m*256 + (n&255)], f32 stores.
    const int R0 = row0 + wm * 128;
    const int C0 = col0 + wn * 64;
#pragma unroll
    for (int mi = 0; mi < 8; ++mi)
#pragma unroll
        for (int ni = 0; ni < 4; ++ni) {
            const int n     = C0 + ni * 16 + lr;
            const int rbase = R0 + mi * 16 + (lane >> 4) * 4;
            const size_t obase = (size_t)(n >> 8) * ((size_t)Mdim * 256) + (n & 255);
#pragma unroll
            for (int j = 0; j < 4; ++j)
                out[obase + (size_t)(rbase + j) * 256] = acc[mi][ni][j];
        }
}

// ---- Fallback (R7-verified): direct-f32 reg-staged dbuf 128^2 kernel ----
constexpr int FBM = 128, FBK = 64;
constexpr int FNWG = (Mdim / FBM) * (Ndim / FBM);
__global__ __launch_bounds__(256)
void gemm_a2a_f32_kernel(const float* __restrict__ X, const float* __restrict__ W,
                         float* __restrict__ out) {
    __shared__ f16 sA[2][FBM * FBK];
    __shared__ f16 sB[2][FBM * FBK];
    const int tid  = threadIdx.x;
    const int lane = tid & 63;
    const int wid  = tid >> 6;
    const int wr   = wid >> 1;
    const int wc   = wid & 1;
    const int cpx  = FNWG >> 3;
    const int tile = (blockIdx.x & 7) * cpx + (blockIdx.x >> 3);
    const int bn   = tile & 15;
    const int bm   = tile >> 4;
    const int row0 = bm * FBM;
    const int col0 = bn * FBM;
    f32x4 acc[4][4] = {};
    f32x4 ra[8], rb[8];
    auto load_tile = [&](int t) {
#pragma unroll
        for (int i = 0; i < 4; ++i) {
            const int c8 = i * 256 + tid;
            const int r  = c8 >> 3;
            const int cc = (c8 & 7) * 8;
            const float* pa = X + (size_t)(row0 + r) * Kdim + t * FBK + cc;
            const float* pb = W + (size_t)(col0 + r) * Kdim + t * FBK + cc;
            ra[2*i] = *(const f32x4*)pa; ra[2*i+1] = *(const f32x4*)(pa + 4);
            rb[2*i] = *(const f32x4*)pb; rb[2*i+1] = *(const f32x4*)(pb + 4);
        }
    };
    int cur = 0;
    load_tile(0);
    for (int t = 0; t < Kdim / FBK; ++t) {
#pragma unroll
        for (int i = 0; i < 4; ++i) {
            const int c8 = i * 256 + tid;
            const int sb = (c8 * 16) ^ (((c8 >> 3) & 7) << 4);
            *(f16x8*)((char*)sA[cur] + sb) = pack8(ra[2*i], ra[2*i+1]);
            *(f16x8*)((char*)sB[cur] + sb) = pack8(rb[2*i], rb[2*i+1]);
        }
        if (t + 1 < Kdim / FBK) load_tile(t + 1);
        __syncthreads();
        const f16* Ab = sA[cur];
        const f16* Bb = sB[cur];
#pragma unroll
        for (int kk = 0; kk < FBK; kk += 32) {
            const int kc = kk + (lane >> 4) * 8;
            f16x8 af[4], bfr[4];
#pragma unroll
            for (int f = 0; f < 4; ++f) {
                const int rowA = wr * 64 + f * 16 + (lane & 15);
                af[f] = *(const f16x8*)((const char*)Ab + (((rowA * FBK + kc) * 2) ^ ((rowA & 7) << 4)));
                const int rowB = wc * 64 + f * 16 + (lane & 15);
                bfr[f] = *(const f16x8*)((const char*)Bb + (((rowB * FBK + kc) * 2) ^ ((rowB & 7) << 4)));
            }
#pragma unroll
            for (int mi = 0; mi < 4; ++mi)
#pragma unroll
                for (int ni = 0; ni < 4; ++ni)
                    acc[mi][ni] = __builtin_amdgcn_mfma_f32_16x16x32_f16(
                        af[mi], bfr[ni], acc[mi][ni], 0, 0, 0);
        }
        cur ^= 1;
    }
#pragma unroll
    for (int mi = 0; mi < 4; ++mi)
#pragma unroll
        for (int ni = 0; ni < 4; ++ni) {
            const int n     = col0 + wc * 64 + ni * 16 + (lane & 15);
            const int rbase = row0 + wr * 64 + mi * 16 + (lane >> 4) * 4;
            const size_t obase = (size_t)(n >> 8) * ((size_t)Mdim * 256) + (n & 255);
#pragma unroll
            for (int j = 0; j < 4; ++j)
                out[obase + (size_t)(rbase + j) * 256] = acc[mi][ni][j];
        }
}

extern "C" void kernel_launch(void* const* d_in, const int* in_sizes, int n_in,
                              void* d_out, int out_size, void* d_ws, size_t ws_size,
                              hipStream_t stream) {
    const float* X = (const float*)d_in[0];
    const float* W = (const float*)d_in[1];
    float* out     = (float*)d_out;
    if (ws_size >= WS_NEED) {
        f16* Xs = (f16*)d_ws;
        f16* Ws = Xs + XS_ELEMS;
        hipLaunchKernelGGL(convert_kernel, dim3((int)(XS_ELEMS / 8 / 256)), dim3(256),
                           0, stream, X, Xs);
        hipLaunchKernelGGL(convert_kernel, dim3((int)(WS_ELEMS / 8 / 256)), dim3(256),
                           0, stream, W, Ws);
        hipLaunchKernelGGL(gemm_a2a_kernel, dim3(NWG), dim3(512), 0, stream, Xs, Ws, out);
    } else {
        hipLaunchKernelGGL(gemm_a2a_f32_kernel, dim3(FNWG), dim3(256), 0, stream, X, W, out);
    }
}